// Round 8
// baseline (48.337 us; speedup 1.0000x reference)
//
#include <hip/hip_runtime.h>
#include <math.h>

#define NN 129
#define INC 129
#define OUTC 64
#define NE 4096

__device__ __forceinline__ float sigmf(float x) { return 1.0f / (1.0f + expf(-x)); }

// D1: block 0 -> all scores + stable descending perm; blocks 1..129 -> dis[node]
__global__ __launch_bounds__(256) void k_prep(
    const float* __restrict__ x, const float* __restrict__ p,
    const int* __restrict__ col, const float* __restrict__ ew,
    float* __restrict__ score, int* __restrict__ perm, float* __restrict__ dis)
{
    int b = blockIdx.x, t = threadIdx.x;
    int wv = t >> 6, lane = t & 63;

    if (b == 0) {
        __shared__ float sp[INC];
        __shared__ float snorm;
        __shared__ float ssc[NN];
        if (t < INC) sp[t] = p[t];
        __syncthreads();
        if (t == 0) {
            float s = 0.f;
            for (int c = 0; c < INC; ++c) s += sp[c] * sp[c];
            snorm = sqrtf(s);
        }
        __syncthreads();
        if (t < NN) {
            float acc = 0.f;
            const float* xr = x + (size_t)t * INC;
            for (int c = 0; c < INC; ++c) acc += xr[c] * sp[c];
            float sc = tanhf(acc / snorm);
            ssc[t] = sc;
            score[t] = sc;
        }
        __syncthreads();
        if (t < NN) {
            float my = ssc[t];
            int rank = 0;
            for (int j = 0; j < NN; ++j) {
                float o = ssc[j];
                rank += (o > my || (o == my && j < t)) ? 1 : 0;   // stable descending
            }
            perm[rank] = t;
        }
    } else {
        __shared__ float red[4];
        int n = b - 1;
        float d = 0.f;
        for (int e = t; e < NE; e += 256) d += (col[e] == n) ? ew[e] : 0.f;
        for (int o = 32; o; o >>= 1) d += __shfl_xor(d, o, 64);
        if (lane == 0) red[wv] = d;
        __syncthreads();
        if (t == 0) {
            float s = 1.0f + red[0] + red[1] + red[2] + red[3];   // +1 self-loop
            dis[n] = rsqrtf(fmaxf(s, 1e-12f));
        }
    }
}

// D2: blocks [0, 4161) -> GRU, one wave per output element (proven pattern);
//     blocks [4161, 4290) -> per-target-node gather aggregation (NO atomics)
#define GRU_BLKS 4161
__global__ __launch_bounds__(256) void k_mid(
    const float* __restrict__ x, const int* __restrict__ ei,
    const float* __restrict__ ew, const float* __restrict__ score,
    const int* __restrict__ perm, const float* __restrict__ dis,
    const float* __restrict__ W0,
    const float* __restrict__ w_ih, const float* __restrict__ w_hh,
    const float* __restrict__ b_ih, const float* __restrict__ b_hh,
    float* __restrict__ W, float* __restrict__ agg)
{
    int b = blockIdx.x, t = threadIdx.x;
    int wv = t >> 6, lane = t & 63;
    const int* row = ei;
    const int* col = ei + NE;

    if (b < GRU_BLKS) {
        int wid = b * 4 + wv;
        if (wid >= NN * INC) return;
        int i = wid / INC;
        int j = wid - i * INC;
        int pi = perm[i];
        float sc = score[pi];
        const float* xr = x  + (size_t)pi * INC;
        const float* h0 = W0 + (size_t)i * INC;
        const float* wr = w_ih + (size_t)j * INC;
        const float* wz = wr + (size_t)INC * INC;
        const float* wn = wz + (size_t)INC * INC;
        const float* vr = w_hh + (size_t)j * INC;
        const float* vz = vr + (size_t)INC * INC;
        const float* vn = vz + (size_t)INC * INC;

        float sr = 0.f, szv = 0.f, an = 0.f, hn = 0.f;
        for (int c = lane; c < INC; c += 64) {
            float xv = xr[c] * sc;
            float hv = h0[c];
            sr  += xv * wr[c] + hv * vr[c];
            szv += xv * wz[c] + hv * vz[c];
            an  += xv * wn[c];
            hn  += hv * vn[c];
        }
        for (int o = 32; o; o >>= 1) {
            sr  += __shfl_xor(sr,  o, 64);
            szv += __shfl_xor(szv, o, 64);
            an  += __shfl_xor(an,  o, 64);
            hn  += __shfl_xor(hn,  o, 64);
        }
        if (lane == 0) {
            float r    = sigmf(sr  + b_ih[j]           + b_hh[j]);
            float z    = sigmf(szv + b_ih[INC + j]     + b_hh[INC + j]);
            float cand = tanhf(an + b_ih[2 * INC + j] + r * (hn + b_hh[2 * INC + j]));
            W[(size_t)i * INC + j] = (1.0f - z) * cand + z * h0[j];
        }
    } else {
        // gather block for target node c: deterministic ballot-compacted edge list
        int c = b - GRU_BLKS;
        __shared__ float s_dis[NN];
        __shared__ int   s_r[512];
        __shared__ float s_w[512];
        __shared__ int   s_cnt;
        __shared__ int   s_wbase[4];
        if (t < NN) s_dis[t] = dis[t];
        if (t == 0) s_cnt = 0;
        __syncthreads();

        for (int base = 0; base < NE; base += 256) {   // NE = 16*256 exact
            int e = base + t;
            int rr = row[e];
            float wval = ew[e];
            bool m = (col[e] == c);
            unsigned long long mask = __ballot(m);
            int wcnt = __popcll(mask);
            if (lane == 0) s_wbase[wv] = wcnt;
            __syncthreads();
            if (t == 0) {
                int acc = s_cnt;
                for (int w = 0; w < 4; ++w) { int v = s_wbase[w]; s_wbase[w] = acc; acc += v; }
                s_cnt = acc;
            }
            __syncthreads();
            if (m) {
                int pos = s_wbase[wv] + __popcll(mask & ((1ull << lane) - 1));
                if (pos < 512) { s_r[pos] = rr; s_w[pos] = wval; }
            }
            __syncthreads();
        }

        int cnt = min(s_cnt, 512);
        float dc = s_dis[c];
        if (t < NN) {
            float a = dc * dc * x[(size_t)c * INC + t];      // self-loop term
            for (int k = 0; k < cnt; ++k) {
                int r = s_r[k];
                float nrm = s_dis[r] * s_w[k] * dc;
                a += nrm * x[(size_t)r * INC + t];
            }
            agg[(size_t)c * INC + t] = a;                    // plain store
        }
    }
}

// D3: per node c — gcn = agg[c] @ W + bias (coalesced W rows), ELU, final linear
__global__ __launch_bounds__(256) void k_fin(
    const float* __restrict__ agg, const float* __restrict__ W,
    const float* __restrict__ cb, const float* __restrict__ lw,
    const float* __restrict__ lb, float* __restrict__ out)
{
    __shared__ float s_a[NN];
    __shared__ float s_h[NN];
    int c = blockIdx.x, t = threadIdx.x;
    int wv = t >> 6, lane = t & 63;

    if (t < NN) s_a[t] = agg[(size_t)c * INC + t];
    __syncthreads();
    if (t < NN) {
        float g = cb[t];
        for (int cc = 0; cc < INC; ++cc) g += s_a[cc] * W[(size_t)cc * INC + t];
        s_h[t] = (g > 0.f) ? g : expm1f(g);    // ELU
    }
    __syncthreads();
    for (int f = wv; f < OUTC; f += 4) {
        const float* wrow = lw + (size_t)f * INC;
        float a = 0.f;
        for (int cc = lane; cc < INC; cc += 64) a += s_h[cc] * wrow[cc];
        for (int o = 32; o; o >>= 1) a += __shfl_xor(a, o, 64);
        if (lane == 0) out[(size_t)c * OUTC + f] = a + lb[f];
    }
}

extern "C" void kernel_launch(void* const* d_in, const int* in_sizes, int n_in,
                              void* d_out, int out_size, void* d_ws, size_t ws_size,
                              hipStream_t stream)
{
    const float* x   = (const float*)d_in[0];
    const int*   ei  = (const int*)d_in[1];
    const float* ew  = (const float*)d_in[2];
    const float* pp  = (const float*)d_in[3];
    const float* W0  = (const float*)d_in[4];
    const float* wih = (const float*)d_in[5];
    const float* whh = (const float*)d_in[6];
    const float* bih = (const float*)d_in[7];
    const float* bhh = (const float*)d_in[8];
    const float* cb  = (const float*)d_in[9];
    const float* lw  = (const float*)d_in[10];
    const float* lb  = (const float*)d_in[11];
    float* out = (float*)d_out;

    char* ws = (char*)d_ws;
    float* score = (float*)(ws + 0);               // 129 f32
    int*   perm  = (int*)  (ws + 640);             // 129 i32
    float* dis   = (float*)(ws + 1280);            // 129 f32
    float* W     = (float*)(ws + 2048);            // 129*129 f32
    float* agg   = (float*)(ws + 2048 + 69632);    // 129*129 f32

    const int* col = ei + NE;

    k_prep<<<NN + 1, 256, 0, stream>>>(x, pp, col, ew, score, perm, dis);

    k_mid<<<GRU_BLKS + NN, 256, 0, stream>>>(
        x, ei, ew, score, perm, dis, W0, wih, whh, bih, bhh, W, agg);

    k_fin<<<NN, 256, 0, stream>>>(agg, W, cb, lw, lb, out);
}

// Round 9
// 35.783 us; speedup vs baseline: 1.3508x; 1.3508x over previous
//
#include <hip/hip_runtime.h>
#include <math.h>

#define NN 129
#define INC 129
#define OUTC 64
#define NE 4096
#define WCAP 32          // per-wave edge-list capacity in D3 (mean ~2, max ~10)

__device__ __forceinline__ float sigmf(float x) { return 1.0f / (1.0f + expf(-x)); }

// D1: block 0 -> all scores (wave-parallel dots) + stable descending rank;
//     blocks 1..129 -> dis[node] via coalesced edge scan
__global__ __launch_bounds__(1024) void k_prep(
    const float* __restrict__ x, const float* __restrict__ p,
    const int* __restrict__ col, const float* __restrict__ ew,
    float* __restrict__ score, int* __restrict__ perm, float* __restrict__ dis)
{
    int b = blockIdx.x, t = threadIdx.x;
    int wv = t >> 6, lane = t & 63;

    if (b == 0) {
        __shared__ float ssc[NN];
        __shared__ float s_rinv;
        if (wv == 0) {
            float a = 0.f;
            for (int c = lane; c < INC; c += 64) { float pv = p[c]; a += pv * pv; }
            for (int o = 32; o; o >>= 1) a += __shfl_xor(a, o, 64);
            if (lane == 0) s_rinv = 1.0f / sqrtf(a);
        }
        // wave-parallel raw dots: wave wv handles nodes wv, wv+16, ...
        for (int n = wv; n < NN; n += 16) {
            const float* xr = x + (size_t)n * INC;
            float a = 0.f;
            for (int c = lane; c < INC; c += 64) a += xr[c] * p[c];
            for (int o = 32; o; o >>= 1) a += __shfl_xor(a, o, 64);
            if (lane == 0) ssc[n] = a;
        }
        __syncthreads();
        if (t < NN) { float sc = tanhf(ssc[t] * s_rinv); ssc[t] = sc; score[t] = sc; }
        __syncthreads();
        if (t < NN) {
            float my = ssc[t];
            int rank = 0;
            #pragma unroll 16
            for (int j = 0; j < NN; ++j) {
                float o = ssc[j];
                rank += (o > my || (o == my && j < t)) ? 1 : 0;   // stable descending
            }
            perm[rank] = t;
        }
    } else {
        __shared__ float red[16];
        int n = b - 1;
        float d = 0.f;
        for (int e = t; e < NE; e += 1024) d += (col[e] == n) ? ew[e] : 0.f;
        for (int o = 32; o; o >>= 1) d += __shfl_xor(d, o, 64);
        if (lane == 0) red[wv] = d;
        __syncthreads();
        if (t == 0) {
            float s = 1.0f;                                      // +1 self-loop
            for (int w = 0; w < 16; ++w) s += red[w];
            dis[n] = rsqrtf(fmaxf(s, 1e-12f));
        }
    }
}

// D2: pure GRU, one wave per output element (i,j) — proven pattern
__global__ __launch_bounds__(256) void k_gru(
    const float* __restrict__ x, const float* __restrict__ score,
    const int* __restrict__ perm, const float* __restrict__ W0,
    const float* __restrict__ w_ih, const float* __restrict__ w_hh,
    const float* __restrict__ b_ih, const float* __restrict__ b_hh,
    float* __restrict__ W)
{
    int lane = threadIdx.x & 63;
    int wid = blockIdx.x * 4 + (threadIdx.x >> 6);
    if (wid >= NN * INC) return;
    int i = wid / INC;
    int j = wid - i * INC;
    int pi = perm[i];
    float sc = score[pi];
    const float* xr = x  + (size_t)pi * INC;
    const float* h0 = W0 + (size_t)i * INC;
    const float* wr = w_ih + (size_t)j * INC;
    const float* wz = wr + (size_t)INC * INC;
    const float* wn = wz + (size_t)INC * INC;
    const float* vr = w_hh + (size_t)j * INC;
    const float* vz = vr + (size_t)INC * INC;
    const float* vn = vz + (size_t)INC * INC;

    float sr = 0.f, szv = 0.f, an = 0.f, hn = 0.f;
    for (int c = lane; c < INC; c += 64) {
        float xv = xr[c] * sc;
        float hv = h0[c];
        sr  += xv * wr[c] + hv * vr[c];
        szv += xv * wz[c] + hv * vz[c];
        an  += xv * wn[c];
        hn  += hv * vn[c];
    }
    for (int o = 32; o; o >>= 1) {
        sr  += __shfl_xor(sr,  o, 64);
        szv += __shfl_xor(szv, o, 64);
        an  += __shfl_xor(an,  o, 64);
        hn  += __shfl_xor(hn,  o, 64);
    }
    if (lane == 0) {
        float r    = sigmf(sr  + b_ih[j]           + b_hh[j]);
        float z    = sigmf(szv + b_ih[INC + j]     + b_hh[INC + j]);
        float cand = tanhf(an + b_ih[2 * INC + j] + r * (hn + b_hh[2 * INC + j]));
        W[(size_t)i * INC + j] = (1.0f - z) * cand + z * h0[j];
    }
}

// D3: per node c — syncless wave-ballot edge list, x-space aggregation in LDS,
//     matvec with column-coalesced W + unroll batching, ELU, final linear
__global__ __launch_bounds__(1024) void k_fin(
    const float* __restrict__ x, const int* __restrict__ ei,
    const float* __restrict__ ew, const float* __restrict__ dis,
    const float* __restrict__ W, const float* __restrict__ cb,
    const float* __restrict__ lw, const float* __restrict__ lb,
    float* __restrict__ out)
{
    __shared__ float s_dis[NN];
    __shared__ int   s_r[16 * WCAP];
    __shared__ float s_w[16 * WCAP];
    __shared__ int   s_cnt[16];
    __shared__ int   s_off[17];
    __shared__ int   s_dr[16 * WCAP];
    __shared__ float s_nrm[16 * WCAP];
    __shared__ float s_a[NN];
    __shared__ float s_h[NN];
    int c = blockIdx.x, t = threadIdx.x;
    int wv = t >> 6, lane = t & 63;
    const int* row = ei;
    const int* col = ei + NE;

    if (t < NN) s_dis[t] = dis[t];

    // edge scan: wave wv owns edges [wv*256, wv*256+256), 4 iters, NO barriers
    int base = wv * 256;
    int cnt = 0;
    #pragma unroll
    for (int it = 0; it < 4; ++it) {
        int e = base + it * 64 + lane;
        int rr = row[e];
        float wval = ew[e];
        bool m = (col[e] == c);
        unsigned long long mask = __ballot(m);
        if (m) {
            int pos = cnt + __popcll(mask & ((1ull << lane) - 1));
            if (pos < WCAP) { s_r[wv * WCAP + pos] = rr; s_w[wv * WCAP + pos] = wval; }
        }
        cnt += __popcll(mask);
    }
    if (lane == 0) s_cnt[wv] = min(cnt, WCAP);
    __syncthreads();

    // prefix over 16 wave counts (thread 0, trivial)
    if (t == 0) {
        int acc = 0;
        for (int w = 0; w < 16; ++w) { s_off[w] = acc; acc += s_cnt[w]; }
        s_off[16] = acc;
    }
    __syncthreads();

    // dense compaction + nrm precompute: wave w, lanes < s_cnt[w]
    float dc = s_dis[c];
    {
        int wc = s_cnt[wv];
        if (lane < wc) {
            int r = s_r[wv * WCAP + lane];
            s_dr[s_off[wv] + lane]  = r;
            s_nrm[s_off[wv] + lane] = s_dis[r] * s_w[wv * WCAP + lane] * dc;
        }
    }
    __syncthreads();

    // aggregate in x-space: thread t = feature f
    int tot = s_off[16];
    if (t < NN) {
        float a = dc * dc * x[(size_t)c * INC + t];       // self-loop term
        #pragma unroll 8
        for (int k = 0; k < tot; ++k)
            a += s_nrm[k] * x[(size_t)s_dr[k] * INC + t];
        s_a[t] = a;
    }
    __syncthreads();

    // matvec: thread t -> gcn[c][t]; W column reads coalesced across lanes
    if (t < NN) {
        float g = cb[t];
        #pragma unroll 16
        for (int cc = 0; cc < NN; ++cc) g += s_a[cc] * W[(size_t)cc * INC + t];
        s_h[t] = (g > 0.f) ? g : expm1f(g);               // ELU
    }
    __syncthreads();

    // final linear: wave per output feature (lw rows coalesced)
    for (int f = wv; f < OUTC; f += 16) {
        const float* wrow = lw + (size_t)f * INC;
        float a = 0.f;
        for (int cc = lane; cc < INC; cc += 64) a += s_h[cc] * wrow[cc];
        for (int o = 32; o; o >>= 1) a += __shfl_xor(a, o, 64);
        if (lane == 0) out[(size_t)c * OUTC + f] = a + lb[f];
    }
}

extern "C" void kernel_launch(void* const* d_in, const int* in_sizes, int n_in,
                              void* d_out, int out_size, void* d_ws, size_t ws_size,
                              hipStream_t stream)
{
    const float* x   = (const float*)d_in[0];
    const int*   ei  = (const int*)d_in[1];
    const float* ew  = (const float*)d_in[2];
    const float* pp  = (const float*)d_in[3];
    const float* W0  = (const float*)d_in[4];
    const float* wih = (const float*)d_in[5];
    const float* whh = (const float*)d_in[6];
    const float* bih = (const float*)d_in[7];
    const float* bhh = (const float*)d_in[8];
    const float* cb  = (const float*)d_in[9];
    const float* lw  = (const float*)d_in[10];
    const float* lb  = (const float*)d_in[11];
    float* out = (float*)d_out;

    char* ws = (char*)d_ws;
    float* score = (float*)(ws + 0);         // 129 f32
    int*   perm  = (int*)  (ws + 640);       // 129 i32
    float* dis   = (float*)(ws + 1280);      // 129 f32
    float* W     = (float*)(ws + 2048);      // 129*129 f32

    const int* col = ei + NE;

    k_prep<<<NN + 1, 1024, 0, stream>>>(x, pp, col, ew, score, perm, dis);

    int gru_blocks = (NN * INC + 3) / 4;     // 4161
    k_gru<<<gru_blocks, 256, 0, stream>>>(x, score, perm, W0, wih, whh, bih, bhh, W);

    k_fin<<<NN, 1024, 0, stream>>>(x, ei, ew, dis, W, cb, lw, lb, out);
}